// Round 2
// baseline (1092.528 us; speedup 1.0000x reference)
//
#include <hip/hip_runtime.h>
#include <hip/hip_bf16.h>
#include <cstdint>

typedef _Float16 f16;
typedef f16 f16x4 __attribute__((ext_vector_type(4)));
typedef f16 f16x8 __attribute__((ext_vector_type(8)));
typedef float f32x4 __attribute__((ext_vector_type(4)));

static constexpr int Hh = 64;   // hidden
static constexpr int Tt = 30;   // seq len
static constexpr int Ii = 9;    // input features
static constexpr int BT = 64;   // batch tile per block
static constexpr int HP = 68;   // padded h-row stride (halves)
static constexpr int XP = 20;   // padded x-row stride (halves)

__device__ __forceinline__ float bf2f(unsigned short u){
  return __uint_as_float(((unsigned int)u) << 16);
}
__device__ __forceinline__ float sigm(float x){ return 1.0f/(1.0f + __expf(-x)); }
// saturating tanh: 1 - 2/(e^{2x}+1); e=inf -> 1, e=0 -> -1 (no inf-inf NaN)
__device__ __forceinline__ float tanh_(float x){ float e = __expf(2.0f*x); return 1.0f - 2.0f/(e + 1.0f); }

template<bool BF16>
__device__ __forceinline__ float ldv(const void* p, long i){
  if constexpr (BF16) return bf2f(((const unsigned short*)p)[i]);
  else                return ((const float*)p)[i];
}

__device__ __forceinline__ f16x8 ld8lds(const f16* p){
  f16x4 lo = *(const f16x4*)p;        // ds_read_b64
  f16x4 hi = *(const f16x4*)(p + 4);  // ds_read_b64
  f16x8 r;
  r[0]=lo[0]; r[1]=lo[1]; r[2]=lo[2]; r[3]=lo[3];
  r[4]=hi[0]; r[5]=hi[1]; r[6]=hi[2]; r[7]=hi[3];
  return r;
}

// Detect whether tensors are bf16 (reinterpreting bf16 pairs as fp32 gives |v| ~ 2^125)
__global__ void detect_dtype(const void* x, int* flag){
  if (threadIdx.x == 0 && blockIdx.x == 0){
    const float* f = (const float*)x;
    int big = 0;
    for (int i = 0; i < 64; ++i){
      float v = f[i];
      if (!(fabsf(v) < 1e10f)) big = 1;   // NaN/Inf/huge -> bf16 data
    }
    *flag = big;
  }
}

// MFMA 16x16x32 f16 mapping (guide §3 / m89,m120):
//   A: m = lane&15, k = (lane>>4)*8 + j   (8 contiguous halves)
//   B: n = lane&15, k = (lane>>4)*8 + j   (= row n of original W[256][K], contiguous k)
//   C/D: n = lane&15, m = (lane>>4)*4 + reg
template<bool BF16>
__device__ void lstm_body(const void* __restrict__ x,
                          const void* __restrict__ Wih0, const void* __restrict__ Whh0,
                          const void* __restrict__ bih0, const void* __restrict__ bhh0,
                          const void* __restrict__ Wih1, const void* __restrict__ Whh1,
                          const void* __restrict__ bih1, const void* __restrict__ bhh1,
                          const void* __restrict__ gmma, const void* __restrict__ beta,
                          void* __restrict__ out,
                          f16* h0s, f16* h1s, f16* xs, float* hfin, float* mus, float* rss)
{
  const int tid  = threadIdx.x;
  const int w    = tid >> 6;      // wave 0..3
  const int lane = tid & 63;
  const int c    = lane & 15;
  const int q    = lane >> 4;
  const long base = (long)blockIdx.x * BT;

  // ---- zero-init state buffers (buf 0) and x staging (both bufs incl. pad) ----
  for (int i = tid; i < BT*HP; i += 256){ h0s[i] = (f16)0.f; h1s[i] = (f16)0.f; }
  for (int i = tid; i < 2*BT*XP; i += 256) xs[i] = (f16)0.f;
  __syncthreads();

  // ---- load weight B-fragments into registers (once) ----
  f16x8 Bhh0v[4][2], Bih1v[4][2], Bhh1v[4][2], Bih0v[4];
  float b0g[4], b1g[4];
  for (int g = 0; g < 4; ++g){
    const int n = 64*g + 16*w + c;
    for (int kt = 0; kt < 2; ++kt){
      const long off = (long)n*64 + kt*32 + q*8;
      for (int j = 0; j < 8; ++j){
        Bhh0v[g][kt][j] = (f16)ldv<BF16>(Whh0, off + j);
        Bih1v[g][kt][j] = (f16)ldv<BF16>(Wih1, off + j);
        Bhh1v[g][kt][j] = (f16)ldv<BF16>(Whh1, off + j);
      }
    }
    f16x8 bi = {};                       // zero-filled: k>=9 contributes 0
    if (q == 0){ for (int j = 0; j < 8; ++j) bi[j] = (f16)ldv<BF16>(Wih0, (long)n*9 + j); }
    else if (q == 1){ bi[0] = (f16)ldv<BF16>(Wih0, (long)n*9 + 8); }
    Bih0v[g] = bi;
    b0g[g] = ldv<BF16>(bih0, n) + ldv<BF16>(bhh0, n);
    b1g[g] = ldv<BF16>(bih1, n) + ldv<BF16>(bhh1, n);
  }

  // ---- stage x for t=0 into xs buf 0 ----
  for (int e = tid; e < BT*Ii; e += 256){
    int s = e / 9, i = e - s*9;
    xs[s*XP + i] = (f16)ldv<BF16>(x, (base + s)*(long)(Tt*Ii) + i);
  }

  float c0[4][4] = {};   // cell state L0: sample mt*16+4q+r, unit 16w+c
  float c1[4][4] = {};
  float xpv[3];
  __syncthreads();

  for (int t = 0; t < Tt; ++t){
    const int rb = t & 1, wb = rb ^ 1;
    f16* h0r = h0s + rb*BT*HP; f16* h0w = h0s + wb*BT*HP;
    f16* h1r = h1s + rb*BT*HP; f16* h1w = h1s + wb*BT*HP;
    f16* xr  = xs  + rb*BT*XP; f16* xw  = xs  + wb*BT*XP;

    // prefetch x(t+1) into regs (hide HBM latency behind MFMA)
    const bool pf = (t + 1 < Tt);
    if (pf){
      int it = 0;
      for (int e = tid; e < BT*Ii; e += 256, ++it){
        int s = e / 9, i = e - s*9;
        xpv[it] = ldv<BF16>(x, (base + s)*(long)(Tt*Ii) + (t+1)*Ii + i);
      }
    }

    // ---- Phase A: layer0 gates = h0 @ Whh0^T + xpad @ Wih0^T + b0 ----
    f16x8 ah[4][2], ax[4];
    for (int mt = 0; mt < 4; ++mt){
      const f16* hp = &h0r[(mt*16 + c)*HP];
      ah[mt][0] = ld8lds(hp + q*8);
      ah[mt][1] = ld8lds(hp + 32 + q*8);
      f16x8 a = {};
      if (q < 2) a = ld8lds(&xr[(mt*16 + c)*XP + q*8]);  // k>=16 lanes supply zeros
      ax[mt] = a;
    }
    f32x4 acc[4][4];
    for (int mt = 0; mt < 4; ++mt)
      for (int g = 0; g < 4; ++g){
        f32x4 a = { b0g[g], b0g[g], b0g[g], b0g[g] };
        a = __builtin_amdgcn_mfma_f32_16x16x32_f16(ah[mt][0], Bhh0v[g][0], a, 0,0,0);
        a = __builtin_amdgcn_mfma_f32_16x16x32_f16(ah[mt][1], Bhh0v[g][1], a, 0,0,0);
        a = __builtin_amdgcn_mfma_f32_16x16x32_f16(ax[mt],    Bih0v[g],    a, 0,0,0);
        acc[mt][g] = a;
      }

    // ---- Phase B: layer0 cell update, h0_new -> LDS ----
    for (int mt = 0; mt < 4; ++mt)
      for (int r = 0; r < 4; ++r){
        float ig = sigm(acc[mt][0][r]);
        float fg = sigm(acc[mt][1][r]);
        float gg = tanh_(acc[mt][2][r]);
        float og = sigm(acc[mt][3][r]);
        float cn = fg*c0[mt][r] + ig*gg;
        c0[mt][r] = cn;
        h0w[(mt*16 + 4*q + r)*HP + 16*w + c] = (f16)(og*tanh_(cn));
      }
    __syncthreads();

    // ---- Phase C: layer1 gates = h0_new @ Wih1^T + h1 @ Whh1^T + b1 ----
    f16x8 a0[4][2], a1[4][2];
    for (int mt = 0; mt < 4; ++mt){
      const f16* p0 = &h0w[(mt*16 + c)*HP];
      a0[mt][0] = ld8lds(p0 + q*8);
      a0[mt][1] = ld8lds(p0 + 32 + q*8);
      const f16* p1 = &h1r[(mt*16 + c)*HP];
      a1[mt][0] = ld8lds(p1 + q*8);
      a1[mt][1] = ld8lds(p1 + 32 + q*8);
    }
    for (int mt = 0; mt < 4; ++mt)
      for (int g = 0; g < 4; ++g){
        f32x4 a = { b1g[g], b1g[g], b1g[g], b1g[g] };
        a = __builtin_amdgcn_mfma_f32_16x16x32_f16(a0[mt][0], Bih1v[g][0], a, 0,0,0);
        a = __builtin_amdgcn_mfma_f32_16x16x32_f16(a0[mt][1], Bih1v[g][1], a, 0,0,0);
        a = __builtin_amdgcn_mfma_f32_16x16x32_f16(a1[mt][0], Bhh1v[g][0], a, 0,0,0);
        a = __builtin_amdgcn_mfma_f32_16x16x32_f16(a1[mt][1], Bhh1v[g][1], a, 0,0,0);
        acc[mt][g] = a;
      }

    // ---- Phase D: layer1 cell update, h1_new -> LDS; last step -> fp32 scratch ----
    for (int mt = 0; mt < 4; ++mt)
      for (int r = 0; r < 4; ++r){
        float ig = sigm(acc[mt][0][r]);
        float fg = sigm(acc[mt][1][r]);
        float gg = tanh_(acc[mt][2][r]);
        float og = sigm(acc[mt][3][r]);
        float cn = fg*c1[mt][r] + ig*gg;
        c1[mt][r] = cn;
        float hh = og*tanh_(cn);
        h1w[(mt*16 + 4*q + r)*HP + 16*w + c] = (f16)hh;
        if (t == Tt-1) hfin[(mt*16 + 4*q + r)*(Hh+1) + 16*w + c] = hh;
      }
    if (pf){
      int it = 0;
      for (int e = tid; e < BT*Ii; e += 256, ++it){
        int s = e / 9, i = e - s*9;
        xw[s*XP + i] = (f16)xpv[it];
      }
    }
    __syncthreads();
  }

  // ---- LayerNorm over final h1 (fp32) ----
  if (tid < BT){
    float s = 0.f, s2 = 0.f;
    for (int u = 0; u < Hh; ++u){ float v = hfin[tid*(Hh+1) + u]; s += v; s2 += v*v; }
    float m   = s  * (1.0f/Hh);
    float var = s2 * (1.0f/Hh) - m*m;     // biased var, matches jnp.var
    mus[tid] = m;
    rss[tid] = rsqrtf(var + 1e-5f);
  }
  __syncthreads();
  for (int itx = 0; itx < (BT*Hh)/256; ++itx){
    int idx = itx*256 + tid;
    int s = idx >> 6, u = idx & 63;
    float v = (hfin[s*(Hh+1) + u] - mus[s]) * rss[s];
    v = v * ldv<BF16>(gmma, u) + ldv<BF16>(beta, u);
    long o = base*Hh + idx;
    if constexpr (BF16) ((__hip_bfloat16*)out)[o] = __float2bfloat16(v);
    else                ((float*)out)[o] = v;
  }
}

__global__ __launch_bounds__(256) void lstm_fused(
    const void* __restrict__ x,
    const void* __restrict__ Wih0, const void* __restrict__ Whh0,
    const void* __restrict__ bih0, const void* __restrict__ bhh0,
    const void* __restrict__ Wih1, const void* __restrict__ Whh1,
    const void* __restrict__ bih1, const void* __restrict__ bhh1,
    const void* __restrict__ gmma, const void* __restrict__ beta,
    void* __restrict__ out, const int* __restrict__ flag)
{
  __shared__ __align__(16) f16 h0s[2*BT*HP];   // 17408 B
  __shared__ __align__(16) f16 h1s[2*BT*HP];   // 17408 B
  __shared__ __align__(16) f16 xs[2*BT*XP];    //  5120 B
  __shared__ float hfin[BT*(Hh+1)];            // 16640 B
  __shared__ float mus[BT], rss[BT];

  if (*flag)
    lstm_body<true >(x, Wih0, Whh0, bih0, bhh0, Wih1, Whh1, bih1, bhh1, gmma, beta,
                     out, h0s, h1s, xs, hfin, mus, rss);
  else
    lstm_body<false>(x, Wih0, Whh0, bih0, bhh0, Wih1, Whh1, bih1, bhh1, gmma, beta,
                     out, h0s, h1s, xs, hfin, mus, rss);
}

extern "C" void kernel_launch(void* const* d_in, const int* in_sizes, int n_in,
                              void* d_out, int out_size, void* d_ws, size_t ws_size,
                              hipStream_t stream) {
  const int B = in_sizes[0] / (Tt * Ii);   // 65536
  int* flag = (int*)d_ws;
  hipLaunchKernelGGL(detect_dtype, dim3(1), dim3(64), 0, stream, d_in[0], flag);
  hipLaunchKernelGGL(lstm_fused, dim3(B / BT), dim3(256), 0, stream,
                     d_in[0], d_in[1], d_in[2], d_in[3], d_in[4], d_in[5], d_in[6],
                     d_in[7], d_in[8], d_in[9], d_in[10], d_out, (const int*)flag);
}